// Round 9
// baseline (364.095 us; speedup 1.0000x reference)
//
#include <hip/hip_runtime.h>
#include <math.h>

#define BATCH_N   32768
#define IN_F      784
#define HID_F     256
#define NCLS      10
#define BM        64          // batch rows per block
#define BK        32          // K per MFMA step
#define NKT       25          // ceil(784/32); kt=24 is the partial tile (peeled)
#define NTHREADS  256

typedef __attribute__((ext_vector_type(8))) short short8;  // 8 bf16 = one MFMA operand frag
typedef __attribute__((ext_vector_type(4))) float f32x4;

// d_ws: w1 pre-converted split-bf16 frag images:
//   slot s = (kt*16 + ct)*64 + lane; byte off = kt*16384 + ct*1024 + lane*16
#define WS_W1H 0
#define WS_W1L 409600          // 25*16*64*16

union S8U { short8 s; uint4 u; };

// fp32x8 -> split bf16 (hi = truncate, lo = exact residual truncated)
__device__ __forceinline__ void cvt8(float4 a, float4 b, short8* hi, short8* lo) {
    const unsigned M = 0xFFFF0000u;
    const unsigned ux = __float_as_uint(a.x), uy = __float_as_uint(a.y),
                   uz = __float_as_uint(a.z), uw = __float_as_uint(a.w),
                   vx = __float_as_uint(b.x), vy = __float_as_uint(b.y),
                   vz = __float_as_uint(b.z), vw = __float_as_uint(b.w);
    S8U h, l;
    h.u.x = (ux >> 16) | (uy & M);
    h.u.y = (uz >> 16) | (uw & M);
    h.u.z = (vx >> 16) | (vy & M);
    h.u.w = (vz >> 16) | (vw & M);
    const float rx = a.x - __uint_as_float(ux & M);
    const float ry = a.y - __uint_as_float(uy & M);
    const float rz = a.z - __uint_as_float(uz & M);
    const float rw = a.w - __uint_as_float(uw & M);
    const float sx = b.x - __uint_as_float(vx & M);
    const float sy = b.y - __uint_as_float(vy & M);
    const float sz = b.z - __uint_as_float(vz & M);
    const float sw_ = b.w - __uint_as_float(vw & M);
    l.u.x = (__float_as_uint(rx) >> 16) | (__float_as_uint(ry) & M);
    l.u.y = (__float_as_uint(rz) >> 16) | (__float_as_uint(rw) & M);
    l.u.z = (__float_as_uint(sx) >> 16) | (__float_as_uint(sy) & M);
    l.u.w = (__float_as_uint(sz) >> 16) | (__float_as_uint(sw_) & M);
    *hi = h.s; *lo = l.s;
}

// ---- pre-pass: w1 -> split-bf16 frag images in d_ws (verified) ----
__global__ __launch_bounds__(256)
void prep_w1_kernel(const float* __restrict__ w1, char* __restrict__ ws) {
    const int s    = blockIdx.x * 256 + threadIdx.x;   // 25600 slots
    const int lane = s & 63, ct = (s >> 6) & 15, kt = s >> 10;
    const int n    = ct * 16 + (lane & 15);
    const int k0   = kt * 32 + (lane >> 4) * 8;
    float4 a = make_float4(0.f, 0.f, 0.f, 0.f), b = a;
    if (k0 + 7 < IN_F) {
        const float* p = w1 + (size_t)n * IN_F + k0;
        a = *(const float4*)p;
        b = *(const float4*)(p + 4);
    }
    short8 hi, lo;
    cvt8(a, b, &hi, &lo);
    *(short8*)(ws + WS_W1H + (size_t)s * 16) = hi;
    *(short8*)(ws + WS_W1L + (size_t)s * 16) = lo;
}

// ---- main: R6 K-loop, 32 KB LDS (two-half epilogue) -> 4 waves/SIMD ----
__global__ __launch_bounds__(NTHREADS, 4)   // VGPR cap 128; 4 blocks/CU target
void mlp_mfma_kernel(const float* __restrict__ x,
                     const char*  __restrict__ wsb,
                     const float* __restrict__ b1,
                     const float* __restrict__ w2,
                     const float* __restrict__ b2,
                     float* __restrict__ out)
{
    __shared__ float hid[32 * HID_F];   // 32 KB: half of the 64-row tile at a time

    const int tid  = threadIdx.x;
    const int wv   = tid >> 6;          // wave: col-tiles ct = 4wv..4wv+3
    const int lane = tid & 63;
    const int m    = lane & 15;
    const int quad = lane >> 4;
    const int row0 = blockIdx.x * BM;
    const int kq   = quad * 8;

    f32x4 acc[4][4];
    #pragma unroll
    for (int a = 0; a < 4; ++a)
        #pragma unroll
        for (int b = 0; b < 4; ++b)
            acc[a][b] = (f32x4){0.f, 0.f, 0.f, 0.f};

    const float* xb[4];
    #pragma unroll
    for (int rt = 0; rt < 4; ++rt)
        xb[rt] = x + (size_t)(row0 + rt * 16 + m) * IN_F;

    const char* bhp = wsb + WS_W1H + ((size_t)(wv * 4) * 64 + lane) * 16;
    const char* blp = wsb + WS_W1L + ((size_t)(wv * 4) * 64 + lane) * 16;

    // prologue: x tile for kt=0
    float4 xc[4][2];
    #pragma unroll
    for (int rt = 0; rt < 4; ++rt) {
        xc[rt][0] = *(const float4*)(xb[rt] + kq);
        xc[rt][1] = *(const float4*)(xb[rt] + kq + 4);
    }

    #pragma unroll 4
    for (int kt = 0; kt < NKT - 1; ++kt) {          // kt = 0..23 [R6-verified]
        short8 bh[4], bl[4];
        #pragma unroll
        for (int c = 0; c < 4; ++c) {
            bh[c] = *(const short8*)(bhp + (size_t)kt * 16384 + c * 1024);
            bl[c] = *(const short8*)(blp + (size_t)kt * 16384 + c * 1024);
        }
        int kon = (kt + 1) * BK + kq;               // clamped x prefetch
        kon = kon > (IN_F - 8) ? (IN_F - 8) : kon;
        float4 xn[4][2];
        #pragma unroll
        for (int rt = 0; rt < 4; ++rt) {
            xn[rt][0] = *(const float4*)(xb[rt] + kon);
            xn[rt][1] = *(const float4*)(xb[rt] + kon + 4);
        }
        short8 ah[4], al[4];
        #pragma unroll
        for (int rt = 0; rt < 4; ++rt)
            cvt8(xc[rt][0], xc[rt][1], &ah[rt], &al[rt]);
        #pragma unroll
        for (int rt = 0; rt < 4; ++rt)
            #pragma unroll
            for (int c = 0; c < 4; ++c) {
                acc[rt][c] = __builtin_amdgcn_mfma_f32_16x16x32_bf16(ah[rt], bh[c], acc[rt][c], 0, 0, 0);
                acc[rt][c] = __builtin_amdgcn_mfma_f32_16x16x32_bf16(al[rt], bh[c], acc[rt][c], 0, 0, 0);
                acc[rt][c] = __builtin_amdgcn_mfma_f32_16x16x32_bf16(ah[rt], bl[c], acc[rt][c], 0, 0, 0);
            }
        #pragma unroll
        for (int rt = 0; rt < 4; ++rt) {
            xc[rt][0] = xn[rt][0];
            xc[rt][1] = xn[rt][1];
        }
    }
    { // peeled tail kt=24 [R6-verified]
        const int kt = NKT - 1;
        short8 bh[4], bl[4];
        #pragma unroll
        for (int c = 0; c < 4; ++c) {
            bh[c] = *(const short8*)(bhp + (size_t)kt * 16384 + c * 1024);
            bl[c] = *(const short8*)(blp + (size_t)kt * 16384 + c * 1024);
        }
        short8 ah[4], al[4];
        #pragma unroll
        for (int rt = 0; rt < 4; ++rt)
            cvt8(xc[rt][0], xc[rt][1], &ah[rt], &al[rt]);
        if (quad >= 2) {                 // k >= 784: zero the A frags
            const short8 zz = {0, 0, 0, 0, 0, 0, 0, 0};
            #pragma unroll
            for (int rt = 0; rt < 4; ++rt) { ah[rt] = zz; al[rt] = zz; }
        }
        #pragma unroll
        for (int rt = 0; rt < 4; ++rt)
            #pragma unroll
            for (int c = 0; c < 4; ++c) {
                acc[rt][c] = __builtin_amdgcn_mfma_f32_16x16x32_bf16(ah[rt], bh[c], acc[rt][c], 0, 0, 0);
                acc[rt][c] = __builtin_amdgcn_mfma_f32_16x16x32_bf16(al[rt], bh[c], acc[rt][c], 0, 0, 0);
                acc[rt][c] = __builtin_amdgcn_mfma_f32_16x16x32_bf16(ah[rt], bl[c], acc[rt][c], 0, 0, 0);
            }
    }

    // ---- two-half epilogue: rows 0..31 (rt 0,1; waves 0,1 do phase 2),
    //      then rows 32..63 (rt 2,3; waves 2,3). Barriers at top level. ----
    #pragma unroll 1
    for (int half = 0; half < 2; ++half) {
        #pragma unroll
        for (int c = 0; c < 4; ++c) {
            const int col = (wv * 4 + c) * 16 + m;
            const float b1v = b1[col];
            #pragma unroll
            for (int rh = 0; rh < 2; ++rh) {
                const int rt = half * 2 + rh;
                #pragma unroll
                for (int reg = 0; reg < 4; ++reg) {
                    const int lrow = rh * 16 + quad * 4 + reg;   // 0..31
                    hid[lrow * 256 + (col ^ ((lrow & 7) << 2))] =
                        fmaxf(acc[rt][c][reg] + b1v, 0.f);
                }
            }
        }
        __syncthreads();
        const int wl = wv - half * 2;                 // participating waves: wl in {0,1}
        if (wl == 0 || wl == 1) {
            const int rl = wl * 16 + m;               // local row 0..31
            const int sw = (rl & 7) << 2;
            const float* hrow = hid + rl * 256;
            float lg[NCLS];
            #pragma unroll
            for (int c = 0; c < NCLS; ++c) lg[c] = 0.f;
            #pragma unroll
            for (int i = 0; i < 8; ++i) {             // [verified, i<8]
                const int h0 = i * 32 + quad * 8;
                const float4 h1 = *(const float4*)(hrow + (h0 ^ sw));
                const float4 h2 = *(const float4*)(hrow + ((h0 + 4) ^ sw));
                #pragma unroll
                for (int c = 0; c < NCLS; ++c) {
                    const float4 wa = *(const float4*)(w2 + c * HID_F + h0);
                    const float4 wb = *(const float4*)(w2 + c * HID_F + h0 + 4);
                    lg[c] += h1.x * wa.x + h1.y * wa.y + h1.z * wa.z + h1.w * wa.w
                           + h2.x * wb.x + h2.y * wb.y + h2.z * wb.z + h2.w * wb.w;
                }
            }
            #pragma unroll
            for (int c = 0; c < NCLS; ++c) {          // reduce over quad-slices
                float v = lg[c];
                v += __shfl_xor(v, 16);
                v += __shfl_xor(v, 32);
                lg[c] = v;
            }
            if (quad == 0) {
                float mx = -1e30f;
                #pragma unroll
                for (int c = 0; c < NCLS; ++c) { lg[c] += b2[c]; mx = fmaxf(mx, lg[c]); }
                float s = 0.f;
                #pragma unroll
                for (int c = 0; c < NCLS; ++c) { lg[c] = __expf(lg[c] - mx); s += lg[c]; }
                const float inv = 1.f / s;
                float* o = out + (size_t)(row0 + half * 32 + rl) * NCLS;
                #pragma unroll
                for (int c = 0; c < NCLS; ++c) o[c] = lg[c] * inv;
            }
        }
        __syncthreads();   // protect hid before the next half overwrites it
    }
}

extern "C" void kernel_launch(void* const* d_in, const int* in_sizes, int n_in,
                              void* d_out, int out_size, void* d_ws, size_t ws_size,
                              hipStream_t stream)
{
    const float* x  = (const float*)d_in[0];
    const float* w1 = (const float*)d_in[1];
    const float* b1 = (const float*)d_in[2];
    const float* w2 = (const float*)d_in[3];
    const float* b2 = (const float*)d_in[4];
    float* out = (float*)d_out;

    hipLaunchKernelGGL(prep_w1_kernel, dim3(100), dim3(256), 0, stream,
                       w1, (char*)d_ws);
    hipLaunchKernelGGL(mlp_mfma_kernel, dim3(BATCH_N / BM), dim3(NTHREADS), 0, stream,
                       x, (const char*)d_ws, b1, w2, b2, out);
}